// Round 7
// baseline (91.621 us; speedup 1.0000x reference)
//
#include <hip/hip_runtime.h>
#include <cfloat>

#define TPB 256
#define Q 8          // queries per thread (register tile)
#define CHUNKS 64    // db chunks (parallelism dimension)
#define LTILE 2048   // LDS tile capacity (floats)
#define RBLK 128     // queries per reduce block
#define ALPHA 0.5f

struct Finale {
    double sx;
    double sy;
    unsigned int ticket;
};

// acc = min(acc, |d0|, |d1|) in ONE VALU instruction (IEEE mode blocks the
// compiler's own min3+abs fusion).
__device__ __forceinline__ float min3abs(float acc, float d0, float d1) {
    float r;
    asm("v_min3_f32 %0, %1, |%2|, |%3|"
        : "=v"(r) : "v"(acc), "v"(d0), "v"(d1));
    return r;
}

// ---------------------------------------------------------------------------
// Scan kernel (R6-proven core, unchanged): db chunk staged to LDS, inner loop
// reads it with all lanes at the same address (hardware broadcast, 0 bank
// conflicts). Per 8 db elems per query: 8 v_sub + 4 v_min3 = 1.5 VALU/visit.
// Additionally block (0,0) thread 0 zero-inits the finale cells; the kernel
// -boundary release publishes them before the reduce kernel's atomics run.
// ---------------------------------------------------------------------------
__global__ __launch_bounds__(TPB) void
chamfer_scan(const float* __restrict__ x, const float* __restrict__ y,
             int n, int m, int nbx, float* __restrict__ partial,
             Finale* __restrict__ fin) {
    __shared__ float s_db[LTILE] __attribute__((aligned(16)));

    if (blockIdx.x == 0 && blockIdx.y == 0 && threadIdx.x == 0) {
        fin->sx = 0.0;
        fin->sy = 0.0;
        fin->ticket = 0u;
    }

    const bool side_x = ((int)blockIdx.y < nbx);          // uniform branch
    const float* __restrict__ qsrc = side_x ? x : y;
    const float* __restrict__ db   = side_x ? y : x;
    const int qn  = side_x ? n : m;
    const int dbn = side_x ? m : n;
    const int by  = side_x ? (int)blockIdx.y : (int)blockIdx.y - nbx;

    const int qoff = (by * TPB + (int)threadIdx.x) * Q;   // within side
    const int total = n + m;
    const int gbase = side_x ? qoff : n + qoff;           // global query idx
    const bool live = (qoff < qn);

    float qv[Q];
#pragma unroll
    for (int k = 0; k < Q; ++k)
        qv[k] = live ? qsrc[min(qoff + k, qn - 1)] : 0.0f;

    const int chunk_len = (dbn + CHUNKS - 1) / CHUNKS;
    const int start = (int)blockIdx.x * chunk_len;
    const int end = min(start + chunk_len, dbn);

    float acc[Q];
#pragma unroll
    for (int k = 0; k < Q; ++k) acc[k] = FLT_MAX;

    for (int ts = start; ts < end; ts += LTILE) {
        const int tlen = min(LTILE, end - ts);
        for (int i = threadIdx.x; i < tlen; i += TPB) s_db[i] = db[ts + i];
        __syncthreads();

        const float4* __restrict__ s4 = (const float4*)s_db;
        const int ng = tlen >> 3;
        for (int g = 0; g < ng; ++g) {
            const float4 a = s4[2 * g];       // ds_read_b128, broadcast
            const float4 b = s4[2 * g + 1];   // ds_read_b128, broadcast
#pragma unroll
            for (int k = 0; k < Q; ++k) {
                const float q = qv[k];
                float acc_k = acc[k];
                acc_k = min3abs(acc_k, a.x - q, a.y - q);
                acc_k = min3abs(acc_k, a.z - q, a.w - q);
                acc_k = min3abs(acc_k, b.x - q, b.y - q);
                acc_k = min3abs(acc_k, b.z - q, b.w - q);
                acc[k] = acc_k;
            }
        }
        for (int j = ng << 3; j < tlen; ++j) {
            const float v = s_db[j];
#pragma unroll
            for (int k = 0; k < Q; ++k) acc[k] = fminf(acc[k], fabsf(qv[k] - v));
        }
        __syncthreads();
    }

    if (!live) return;
    float* __restrict__ dst = partial + (size_t)blockIdx.x * total + gbase;
    if (qoff + Q <= qn) {
#pragma unroll
        for (int k = 0; k < Q; ++k) dst[k] = acc[k];
    } else {
#pragma unroll
        for (int k = 0; k < Q; ++k)
            if (qoff + k < qn) dst[k] = acc[k];
    }
}

// ---------------------------------------------------------------------------
// Fused reduce: per-query min over CHUNKS partials (coalesced), block-level
// double sums, then device-scope fp64 atomicAdd into the finale cells; the
// last block (ticket) reads them back via atomic RMW and writes the loss.
// ---------------------------------------------------------------------------
__global__ __launch_bounds__(TPB) void
chamfer_reduce(const float* __restrict__ vals, int n, int m,
               Finale* __restrict__ fin, float* __restrict__ out) {
    const int total = n + m;
    const int lq = threadIdx.x & (RBLK - 1);   // query within block
    const int h = threadIdx.x >> 7;            // chunk half (0/1)
    const int q = blockIdx.x * RBLK + lq;

    float mv = FLT_MAX;
    if (q < total) {
        const int c0 = h * (CHUNKS / 2), c1 = c0 + CHUNKS / 2;
        for (int c = c0; c < c1; ++c)
            mv = fminf(mv, vals[(size_t)c * total + q]);
    }
    __shared__ float half1[RBLK];
    if (h == 1) half1[lq] = mv;
    __syncthreads();

    double sx = 0.0, sy = 0.0;
    if (h == 0 && q < total) {
        const float best = fminf(mv, half1[lq]);
        if (q < n) sx = (double)best; else sy = (double)best;
    }
    for (int off = 32; off > 0; off >>= 1) {
        sx += __shfl_down(sx, off);
        sy += __shfl_down(sy, off);
    }
    __shared__ double wsx[2], wsy[2];
    if (h == 0 && (threadIdx.x & 63) == 0) {
        wsx[threadIdx.x >> 6] = sx;
        wsy[threadIdx.x >> 6] = sy;
    }
    __syncthreads();
    if (threadIdx.x == 0) {
        const double tx = wsx[0] + wsx[1];
        const double ty = wsy[0] + wsy[1];
        atomicAdd(&fin->sx, tx);            // device-scope f64 atomic
        atomicAdd(&fin->sy, ty);
        __threadfence();                    // publish before taking ticket
        const unsigned int t = __hip_atomic_fetch_add(
            &fin->ticket, 1u, __ATOMIC_ACQ_REL, __HIP_MEMORY_SCOPE_AGENT);
        if (t == (unsigned int)gridDim.x - 1u) {
            // Last block: all adds are visible. Read back via device-scope RMW.
            const double fx = atomicAdd(&fin->sx, 0.0);
            const double fy = atomicAdd(&fin->sy, 0.0);
            const double a = (double)ALPHA;
            out[0] = (float)(a * fx / (double)n + (1.0 - a) * fy / (double)m);
        }
    }
}

extern "C" void kernel_launch(void* const* d_in, const int* in_sizes, int n_in,
                              void* d_out, int out_size, void* d_ws, size_t ws_size,
                              hipStream_t stream) {
    const float* x = (const float*)d_in[0];
    const float* y = (const float*)d_in[1];
    const int n = in_sizes[0];
    const int m = in_sizes[1];
    float* out = (float*)d_out;
    const int total = n + m;

    const int qpb = TPB * Q;                       // queries per block
    const int nbx = (n + qpb - 1) / qpb;
    const int nby = (m + qpb - 1) / qpb;
    const dim3 grid1(CHUNKS, nbx + nby);
    const int nb1 = (total + RBLK - 1) / RBLK;

    const size_t partial_bytes = (size_t)CHUNKS * total * sizeof(float);
    const size_t partial_aligned = (partial_bytes + 255) & ~(size_t)255;

    float* partial = (float*)d_ws;
    Finale* fin = (Finale*)((char*)d_ws + partial_aligned);

    chamfer_scan<<<grid1, TPB, 0, stream>>>(x, y, n, m, nbx, partial, fin);
    chamfer_reduce<<<nb1, TPB, 0, stream>>>(partial, n, m, fin, out);
}

// Round 8
// 89.484 us; speedup vs baseline: 1.0239x; 1.0239x over previous
//
#include <hip/hip_runtime.h>
#include <cfloat>

#define TPB 256
#define Q 8          // queries per thread (register tile)
#define CHUNKS 128   // db chunks -> 2048 blocks = 8 waves/SIMD (TLP probe)
#define LTILE 2048   // LDS tile capacity (floats)
#define RBLK 128     // queries per reduce1 block
#define ALPHA 0.5f

// acc = min(acc, |d0|, |d1|) in ONE VALU instruction (IEEE mode blocks the
// compiler's own min3+abs fusion).
__device__ __forceinline__ float min3abs(float acc, float d0, float d1) {
    float r;
    asm("v_min3_f32 %0, %1, |%2|, |%3|"
        : "=v"(r) : "v"(acc), "v"(d0), "v"(d1));
    return r;
}

// ---------------------------------------------------------------------------
// Scan kernel (R6-proven core): db chunk staged to LDS cooperatively, inner
// loop reads it with all lanes at the same address (hardware broadcast, zero
// bank conflicts). Per 8 db elems per query: 8 v_sub + 4 v_min3 = 1.5
// VALU/visit. Grid gives 8 blocks/CU -> 8 waves/SIMD for latency hiding.
// ---------------------------------------------------------------------------
__global__ __launch_bounds__(TPB) void
chamfer_scan(const float* __restrict__ x, const float* __restrict__ y,
             int n, int m, int nbx, float* __restrict__ partial) {
    __shared__ float s_db[LTILE] __attribute__((aligned(16)));

    const bool side_x = ((int)blockIdx.y < nbx);          // uniform branch
    const float* __restrict__ qsrc = side_x ? x : y;
    const float* __restrict__ db   = side_x ? y : x;
    const int qn  = side_x ? n : m;
    const int dbn = side_x ? m : n;
    const int by  = side_x ? (int)blockIdx.y : (int)blockIdx.y - nbx;

    const int qoff = (by * TPB + (int)threadIdx.x) * Q;   // within side
    const int total = n + m;
    const int gbase = side_x ? qoff : n + qoff;           // global query idx
    const bool live = (qoff < qn);

    float qv[Q];
#pragma unroll
    for (int k = 0; k < Q; ++k)
        qv[k] = live ? qsrc[min(qoff + k, qn - 1)] : 0.0f;

    const int chunk_len = (dbn + CHUNKS - 1) / CHUNKS;
    const int start = (int)blockIdx.x * chunk_len;
    const int end = min(start + chunk_len, dbn);

    float acc[Q];
#pragma unroll
    for (int k = 0; k < Q; ++k) acc[k] = FLT_MAX;

    for (int ts = start; ts < end; ts += LTILE) {
        const int tlen = min(LTILE, end - ts);
        for (int i = threadIdx.x; i < tlen; i += TPB) s_db[i] = db[ts + i];
        __syncthreads();

        const float4* __restrict__ s4 = (const float4*)s_db;
        const int ng = tlen >> 3;
        for (int g = 0; g < ng; ++g) {
            const float4 a = s4[2 * g];       // ds_read_b128, broadcast
            const float4 b = s4[2 * g + 1];   // ds_read_b128, broadcast
#pragma unroll
            for (int k = 0; k < Q; ++k) {
                const float q = qv[k];
                float acc_k = acc[k];
                acc_k = min3abs(acc_k, a.x - q, a.y - q);
                acc_k = min3abs(acc_k, a.z - q, a.w - q);
                acc_k = min3abs(acc_k, b.x - q, b.y - q);
                acc_k = min3abs(acc_k, b.z - q, b.w - q);
                acc[k] = acc_k;
            }
        }
        for (int j = ng << 3; j < tlen; ++j) {
            const float v = s_db[j];
#pragma unroll
            for (int k = 0; k < Q; ++k) acc[k] = fminf(acc[k], fabsf(qv[k] - v));
        }
        __syncthreads();
    }

    if (!live) return;
    float* __restrict__ dst = partial + (size_t)blockIdx.x * total + gbase;
    if (qoff + Q <= qn) {
#pragma unroll
        for (int k = 0; k < Q; ++k) dst[k] = acc[k];
    } else {
#pragma unroll
        for (int k = 0; k < Q; ++k)
            if (qoff + k < qn) dst[k] = acc[k];
    }
}

// Reduce 1: one block per RBLK contiguous queries. 256 threads =
// RBLK queries x 2 chunk-halves; lanes read consecutive queries (coalesced).
__global__ __launch_bounds__(TPB) void
chamfer_reduce1(const float* __restrict__ vals, int n, int m,
                double* __restrict__ bsums) {
    const int total = n + m;
    const int lq = threadIdx.x & (RBLK - 1);   // query within block
    const int h = threadIdx.x >> 7;            // chunk half (0/1)
    const int q = blockIdx.x * RBLK + lq;

    float mv = FLT_MAX;
    if (q < total) {
        const int c0 = h * (CHUNKS / 2), c1 = c0 + CHUNKS / 2;
        for (int c = c0; c < c1; ++c)
            mv = fminf(mv, vals[(size_t)c * total + q]);
    }
    __shared__ float half1[RBLK];
    if (h == 1) half1[lq] = mv;
    __syncthreads();

    double sx = 0.0, sy = 0.0;
    if (h == 0 && q < total) {
        const float best = fminf(mv, half1[lq]);
        if (q < n) sx = (double)best; else sy = (double)best;
    }
    for (int off = 32; off > 0; off >>= 1) {
        sx += __shfl_down(sx, off);
        sy += __shfl_down(sy, off);
    }
    __shared__ double wsx[2], wsy[2];
    if (h == 0 && (threadIdx.x & 63) == 0) {
        wsx[threadIdx.x >> 6] = sx;
        wsy[threadIdx.x >> 6] = sy;
    }
    __syncthreads();
    if (threadIdx.x == 0) {
        bsums[2 * blockIdx.x]     = wsx[0] + wsx[1];
        bsums[2 * blockIdx.x + 1] = wsy[0] + wsy[1];
    }
}

// Reduce 2: fold nb block sums -> scalar loss.
__global__ __launch_bounds__(TPB) void
chamfer_reduce2(const double* __restrict__ bsums, int nb,
                int n, int m, float* __restrict__ out) {
    double sx = 0.0, sy = 0.0;
    for (int i = threadIdx.x; i < nb; i += blockDim.x) {
        sx += bsums[2 * i];
        sy += bsums[2 * i + 1];
    }
    for (int off = 32; off > 0; off >>= 1) {
        sx += __shfl_down(sx, off);
        sy += __shfl_down(sy, off);
    }
    __shared__ double lsx[4], lsy[4];
    const int wave = threadIdx.x >> 6;
    if ((threadIdx.x & 63) == 0) { lsx[wave] = sx; lsy[wave] = sy; }
    __syncthreads();
    if (threadIdx.x == 0) {
        double tx = 0.0, ty = 0.0;
        for (int w = 0; w < (int)(blockDim.x >> 6); ++w) { tx += lsx[w]; ty += lsy[w]; }
        const double a = (double)ALPHA;
        out[0] = (float)(a * tx / (double)n + (1.0 - a) * ty / (double)m);
    }
}

extern "C" void kernel_launch(void* const* d_in, const int* in_sizes, int n_in,
                              void* d_out, int out_size, void* d_ws, size_t ws_size,
                              hipStream_t stream) {
    const float* x = (const float*)d_in[0];
    const float* y = (const float*)d_in[1];
    const int n = in_sizes[0];
    const int m = in_sizes[1];
    float* out = (float*)d_out;
    const int total = n + m;

    const int qpb = TPB * Q;                       // queries per block
    const int nbx = (n + qpb - 1) / qpb;
    const int nby = (m + qpb - 1) / qpb;
    const dim3 grid1(CHUNKS, nbx + nby);
    const int nb1 = (total + RBLK - 1) / RBLK;

    const size_t partial_bytes = (size_t)CHUNKS * total * sizeof(float);
    const size_t partial_aligned = (partial_bytes + 255) & ~(size_t)255;

    float* partial = (float*)d_ws;
    double* bsums = (double*)((char*)d_ws + partial_aligned);

    chamfer_scan<<<grid1, TPB, 0, stream>>>(x, y, n, m, nbx, partial);
    chamfer_reduce1<<<nb1, TPB, 0, stream>>>(partial, n, m, bsums);
    chamfer_reduce2<<<1, TPB, 0, stream>>>(bsums, nb1, n, m, out);
}

// Round 9
// 80.319 us; speedup vs baseline: 1.1407x; 1.1141x over previous
//
#include <hip/hip_runtime.h>
#include <cfloat>

#define TPB 256
#define Q 8          // queries per thread (register tile)
#define CHUNKS 64    // db chunks -> 1024 blocks = 4 waves/SIMD (R6-proven)
#define LTILE 2048   // LDS tile capacity (floats)
#define RBLK 128     // queries per reduce1 block
#define ALPHA 0.5f

// acc = min(acc, |d0|, |d1|) in ONE VALU instruction (IEEE mode blocks the
// compiler's own min3+abs fusion).
__device__ __forceinline__ float min3abs(float acc, float d0, float d1) {
    float r;
    asm("v_min3_f32 %0, %1, |%2|, |%3|"
        : "=v"(r) : "v"(acc), "v"(d0), "v"(d1));
    return r;
}

__device__ __forceinline__ void group_compute(const float4 a, const float4 b,
                                              const float qv[Q], float acc[Q]) {
#pragma unroll
    for (int k = 0; k < Q; ++k) {
        const float q = qv[k];
        float acc_k = acc[k];
        acc_k = min3abs(acc_k, a.x - q, a.y - q);
        acc_k = min3abs(acc_k, a.z - q, a.w - q);
        acc_k = min3abs(acc_k, b.x - q, b.y - q);
        acc_k = min3abs(acc_k, b.z - q, b.w - q);
        acc[k] = acc_k;
    }
}

// ---------------------------------------------------------------------------
// Scan kernel (R6 core + software-pipelined LDS reads): db chunk staged to
// LDS cooperatively; inner loop reads it with all lanes at the same address
// (hardware broadcast, 0 bank conflicts). Group g+1's ds_read_b128 pair is
// issued before group g's 96 VALU instructions, hiding the ds latency even
// for a single wave. 8 v_sub + 4 v_min3 per 8 visits = 1.5 VALU/visit.
// ---------------------------------------------------------------------------
__global__ __launch_bounds__(TPB) void
chamfer_scan(const float* __restrict__ x, const float* __restrict__ y,
             int n, int m, int nbx, float* __restrict__ partial) {
    __shared__ float s_db[LTILE] __attribute__((aligned(16)));

    const bool side_x = ((int)blockIdx.y < nbx);          // uniform branch
    const float* __restrict__ qsrc = side_x ? x : y;
    const float* __restrict__ db   = side_x ? y : x;
    const int qn  = side_x ? n : m;
    const int dbn = side_x ? m : n;
    const int by  = side_x ? (int)blockIdx.y : (int)blockIdx.y - nbx;

    const int qoff = (by * TPB + (int)threadIdx.x) * Q;   // within side
    const int total = n + m;
    const int gbase = side_x ? qoff : n + qoff;           // global query idx
    const bool live = (qoff < qn);

    float qv[Q];
    if (live && qoff + Q <= qn) {
        // qoff is a multiple of 8 floats -> 32B-aligned: 2x global_load_dwordx4
        const float4* __restrict__ q4 = (const float4*)(qsrc + qoff);
        const float4 qa = q4[0], qb = q4[1];
        qv[0] = qa.x; qv[1] = qa.y; qv[2] = qa.z; qv[3] = qa.w;
        qv[4] = qb.x; qv[5] = qb.y; qv[6] = qb.z; qv[7] = qb.w;
    } else {
#pragma unroll
        for (int k = 0; k < Q; ++k)
            qv[k] = live ? qsrc[min(qoff + k, qn - 1)] : 0.0f;
    }

    const int chunk_len = (dbn + CHUNKS - 1) / CHUNKS;
    const int start = (int)blockIdx.x * chunk_len;
    const int end = min(start + chunk_len, dbn);

    float acc[Q];
#pragma unroll
    for (int k = 0; k < Q; ++k) acc[k] = FLT_MAX;

    for (int ts = start; ts < end; ts += LTILE) {
        const int tlen = min(LTILE, end - ts);
        for (int i = threadIdx.x; i < tlen; i += TPB) s_db[i] = db[ts + i];
        __syncthreads();

        const float4* __restrict__ s4 = (const float4*)s_db;
        const int ng = tlen >> 3;
        if (ng > 0) {
            // Software pipeline: prefetch g+1 before computing g.
            float4 a0 = s4[0], b0 = s4[1];
            int g = 0;
            for (; g + 1 < ng; ++g) {
                const float4 a1 = s4[2 * g + 2];   // ds_read_b128 (next)
                const float4 b1 = s4[2 * g + 3];   // ds_read_b128 (next)
                group_compute(a0, b0, qv, acc);    // 96 VALU on current
                a0 = a1; b0 = b1;
            }
            group_compute(a0, b0, qv, acc);        // peeled last group
        }
        for (int j = ng << 3; j < tlen; ++j) {
            const float v = s_db[j];
#pragma unroll
            for (int k = 0; k < Q; ++k) acc[k] = fminf(acc[k], fabsf(qv[k] - v));
        }
        __syncthreads();
    }

    if (!live) return;
    float* __restrict__ dst = partial + (size_t)blockIdx.x * total + gbase;
    if (qoff + Q <= qn) {
#pragma unroll
        for (int k = 0; k < Q; ++k) dst[k] = acc[k];
    } else {
#pragma unroll
        for (int k = 0; k < Q; ++k)
            if (qoff + k < qn) dst[k] = acc[k];
    }
}

// Reduce 1: one block per RBLK contiguous queries. 256 threads =
// RBLK queries x 2 chunk-halves; lanes read consecutive queries (coalesced).
__global__ __launch_bounds__(TPB) void
chamfer_reduce1(const float* __restrict__ vals, int n, int m,
                double* __restrict__ bsums) {
    const int total = n + m;
    const int lq = threadIdx.x & (RBLK - 1);   // query within block
    const int h = threadIdx.x >> 7;            // chunk half (0/1)
    const int q = blockIdx.x * RBLK + lq;

    float mv = FLT_MAX;
    if (q < total) {
        const int c0 = h * (CHUNKS / 2), c1 = c0 + CHUNKS / 2;
        for (int c = c0; c < c1; ++c)
            mv = fminf(mv, vals[(size_t)c * total + q]);
    }
    __shared__ float half1[RBLK];
    if (h == 1) half1[lq] = mv;
    __syncthreads();

    double sx = 0.0, sy = 0.0;
    if (h == 0 && q < total) {
        const float best = fminf(mv, half1[lq]);
        if (q < n) sx = (double)best; else sy = (double)best;
    }
    for (int off = 32; off > 0; off >>= 1) {
        sx += __shfl_down(sx, off);
        sy += __shfl_down(sy, off);
    }
    __shared__ double wsx[2], wsy[2];
    if (h == 0 && (threadIdx.x & 63) == 0) {
        wsx[threadIdx.x >> 6] = sx;
        wsy[threadIdx.x >> 6] = sy;
    }
    __syncthreads();
    if (threadIdx.x == 0) {
        bsums[2 * blockIdx.x]     = wsx[0] + wsx[1];
        bsums[2 * blockIdx.x + 1] = wsy[0] + wsy[1];
    }
}

// Reduce 2: fold nb block sums -> scalar loss.
__global__ __launch_bounds__(TPB) void
chamfer_reduce2(const double* __restrict__ bsums, int nb,
                int n, int m, float* __restrict__ out) {
    double sx = 0.0, sy = 0.0;
    for (int i = threadIdx.x; i < nb; i += blockDim.x) {
        sx += bsums[2 * i];
        sy += bsums[2 * i + 1];
    }
    for (int off = 32; off > 0; off >>= 1) {
        sx += __shfl_down(sx, off);
        sy += __shfl_down(sy, off);
    }
    __shared__ double lsx[4], lsy[4];
    const int wave = threadIdx.x >> 6;
    if ((threadIdx.x & 63) == 0) { lsx[wave] = sx; lsy[wave] = sy; }
    __syncthreads();
    if (threadIdx.x == 0) {
        double tx = 0.0, ty = 0.0;
        for (int w = 0; w < (int)(blockDim.x >> 6); ++w) { tx += lsx[w]; ty += lsy[w]; }
        const double a = (double)ALPHA;
        out[0] = (float)(a * tx / (double)n + (1.0 - a) * ty / (double)m);
    }
}

extern "C" void kernel_launch(void* const* d_in, const int* in_sizes, int n_in,
                              void* d_out, int out_size, void* d_ws, size_t ws_size,
                              hipStream_t stream) {
    const float* x = (const float*)d_in[0];
    const float* y = (const float*)d_in[1];
    const int n = in_sizes[0];
    const int m = in_sizes[1];
    float* out = (float*)d_out;
    const int total = n + m;

    const int qpb = TPB * Q;                       // queries per block
    const int nbx = (n + qpb - 1) / qpb;
    const int nby = (m + qpb - 1) / qpb;
    const dim3 grid1(CHUNKS, nbx + nby);
    const int nb1 = (total + RBLK - 1) / RBLK;

    const size_t partial_bytes = (size_t)CHUNKS * total * sizeof(float);
    const size_t partial_aligned = (partial_bytes + 255) & ~(size_t)255;

    float* partial = (float*)d_ws;
    double* bsums = (double*)((char*)d_ws + partial_aligned);

    chamfer_scan<<<grid1, TPB, 0, stream>>>(x, y, n, m, nbx, partial);
    chamfer_reduce1<<<nb1, TPB, 0, stream>>>(partial, n, m, bsums);
    chamfer_reduce2<<<1, TPB, 0, stream>>>(bsums, nb1, n, m, out);
}